// Round 16
// baseline (438.813 us; speedup 1.0000x reference)
//
#include <hip/hip_runtime.h>

// LiftSplatShot voxel pooling: segment-sum of per-point features into a
// (B=2, C=64, 512, 512) fp32 grid.
//
// NUMERICS (FROZEN — r5): jitted-XLA semantics
//   q = RN32( RN32(f + 51.2f) * 5.0f ) (x/y; recip(0.2f) folds to exactly 5.0f)
//   qz = RN32( RN32(f + 5.0f) * 0.125f ); trunc; kept: px,py in [0,512), pz==0.
//
// r16 = ABLATION LEVEL 2. r15 established: gather+ds_add phase == 200us,
// stores free (NT==plain, probe-without-stores==200). Now split that phase:
//   probe_empty: prologue + barriers + guarded epilogue (fixed block cost)
//   probe_lds:   ds_add pattern only (values synthesized from ent)
//   probe_load:  x-loads only (folded to registers, no LDS atomics)
// All same launch shape/LDS/bounds as accum. Read durations from top-5 rows
// (distinct names) + dur_us subtraction.

#define NX0 512
#define NX1 512
#define CDIM 64
#define TSPAT 64             // 1(px) x 64(py) voxels per tile
#define NTILE 8192           // 2 * 512 * 8
#define CAP 256
#define LSTRIDE 65
#define CNT_PAD 16

typedef float v4f __attribute__((ext_vector_type(4)));

__device__ __forceinline__ bool voxel_of(float fx, float fy, float fz,
                                         int& px, int& py) {
    float qx = (fx + 51.2f) * 5.0f;
    float qy = (fy + 51.2f) * 5.0f;
    float qz = (fz + 5.0f) * 0.125f;
    px = (int)qx; py = (int)qy;
    int pz = (int)qz;
    return (px >= 0 && px < NX0 && py >= 0 && py < NX1 && pz == 0);
}

// A: bin points into fixed-capacity per-tile lists
__global__ __launch_bounds__(256) void lss_bin(
    const float* __restrict__ points, unsigned* __restrict__ plist,
    int* __restrict__ cnt, int npoints, int per_batch)
{
    int i = blockIdx.x * 256 + threadIdx.x;
    if (i >= npoints) return;
    float fx = points[(size_t)i * 3 + 0];
    float fy = points[(size_t)i * 3 + 1];
    float fz = points[(size_t)i * 3 + 2];
    int px, py;
    if (!voxel_of(fx, fy, fz, px, py)) return;
    int b = (i >= per_batch) ? 1 : 0;
    unsigned tid = ((unsigned)b << 12) | ((unsigned)px << 3) | ((unsigned)py >> 6);
    unsigned s = (unsigned)(py & 63);
    int slot = atomicAdd(&cnt[tid * CNT_PAD], 1);
    if (slot < CAP) plist[(size_t)tid * CAP + slot] = ((unsigned)i << 6) | s;
}

__device__ __forceinline__ void zero_acc(float* acc, int t) {
    v4f z = (v4f)(0.0f);
    v4f* acc4 = (v4f*)acc;
    #pragma unroll
    for (int j = 0; j < 5; ++j) { int i = t + j * 256; if (i < 1040) acc4[i] = z; }
}

// D: real accumulate (r14 winner, plain stores)
__global__ __launch_bounds__(256, 8) void lss_accum(
    const unsigned* __restrict__ plist, const int* __restrict__ cnt,
    const float* __restrict__ x, float* __restrict__ out)
{
    __shared__ float acc[TSPAT * LSTRIDE];
    __shared__ unsigned ent[CAP];
    int tile = blockIdx.x;
    int t = threadIdx.x;

    int n = cnt[tile * CNT_PAD];
    if (n > CAP) n = CAP;

    zero_acc(acc, t);
    const unsigned* pl = plist + (size_t)tile * CAP;
    if (t < n) ent[t] = pl[t];
    __syncthreads();

    if (n > 0) {
        int lane = t & 63, w = t >> 6, pg = lane >> 4, cg = lane & 15;
        int p0 = w * 4 + pg, coff = cg * 4;
        int trips = 0; { int rem = n - w * 4; if (rem > 0) trips = (rem + 15) >> 4; }
        unsigned e0, e1, e2, e3; v4f v0, v1, v2, v3;
        int s0, s1, s2, s3; bool a0, a1, a2, a3;
        #define LOADP(TR, E, V, S, A)                                          \
            { int p = p0 + ((TR) << 4); (A) = p < n;                           \
              (E) = ent[(A) ? p : 0]; (S) = (int)((E) & 63u);                  \
              if (A) (V) = *(const v4f*)(x + ((size_t)((E) >> 6)) * CDIM + coff); }
        #define CONSUME(V, S, A)                                               \
            if (A) { int bse = (S) * LSTRIDE + coff;                           \
                atomicAdd(&acc[bse + 0], (V).x); atomicAdd(&acc[bse + 1], (V).y); \
                atomicAdd(&acc[bse + 2], (V).z); atomicAdd(&acc[bse + 3], (V).w); }
        LOADP(0, e0, v0, s0, a0) LOADP(1, e1, v1, s1, a1)
        LOADP(2, e2, v2, s2, a2) LOADP(3, e3, v3, s3, a3)
        int tr = 0;
        while (tr + 4 < trips) {
            CONSUME(v0, s0, a0) LOADP(tr + 4, e0, v0, s0, a0)
            CONSUME(v1, s1, a1) LOADP(tr + 5, e1, v1, s1, a1)
            CONSUME(v2, s2, a2) LOADP(tr + 6, e2, v2, s2, a2)
            CONSUME(v3, s3, a3) LOADP(tr + 7, e3, v3, s3, a3)
            tr += 4;
        }
        CONSUME(v0, s0, a0) CONSUME(v1, s1, a1)
        CONSUME(v2, s2, a2) CONSUME(v3, s3, a3)
        #undef LOADP
        #undef CONSUME
    }
    __syncthreads();

    int b   = tile >> 12;
    int px  = (tile >> 3) & 511;
    int py0 = (tile & 7) << 6;
    int w = t >> 6, lane = t & 63;
    int l16 = lane & 15, grp = lane >> 4;
    #pragma unroll
    for (int j = 0; j < 4; ++j) {
        int cc = j * 16 + w * 4 + grp;
        int sb = l16 * 4;
        v4f o;
        o.x = acc[(sb + 0) * LSTRIDE + cc];
        o.y = acc[(sb + 1) * LSTRIDE + cc];
        o.z = acc[(sb + 2) * LSTRIDE + cc];
        o.w = acc[(sb + 3) * LSTRIDE + cc];
        size_t oidx = (((size_t)(b * CDIM + cc)) << 18)
                    + ((size_t)px << 9) + (size_t)(py0 + sb);
        *(v4f*)(out + oidx) = o;
    }
}

// PROBE 1: fixed block cost only (zero LDS + barriers + guarded epilogue)
__global__ __launch_bounds__(256, 8) void lss_probe_empty(
    const int* __restrict__ cnt, float* __restrict__ sink)
{
    __shared__ float acc[TSPAT * LSTRIDE];
    int tile = blockIdx.x;
    int t = threadIdx.x;
    int n_raw = cnt[tile * CNT_PAD];
    zero_acc(acc, t);
    __syncthreads();
    __syncthreads();
    if (n_raw == 0x7FFFFFFF) {
        #pragma unroll
        for (int j = 0; j < 4; ++j) sink[t + j * 256] = acc[(t + j * 256) % (TSPAT * LSTRIDE)];
    }
}

// PROBE 2: ds_add pattern only; values synthesized from ent (no x loads)
__global__ __launch_bounds__(256, 8) void lss_probe_lds(
    const unsigned* __restrict__ plist, const int* __restrict__ cnt,
    float* __restrict__ sink)
{
    __shared__ float acc[TSPAT * LSTRIDE];
    __shared__ unsigned ent[CAP];
    int tile = blockIdx.x;
    int t = threadIdx.x;
    int n_raw = cnt[tile * CNT_PAD];
    int n = n_raw > CAP ? CAP : n_raw;
    zero_acc(acc, t);
    const unsigned* pl = plist + (size_t)tile * CAP;
    if (t < n) ent[t] = pl[t];
    __syncthreads();
    if (n > 0) {
        int lane = t & 63, w = t >> 6, pg = lane >> 4, cg = lane & 15;
        int p0 = w * 4 + pg, coff = cg * 4;
        for (int p = p0; p < n; p += 16) {
            unsigned e = ent[p];
            int s = (int)(e & 63u);
            float vv = (float)(e >> 6);          // synthesized value (VALU only)
            int bse = s * LSTRIDE + coff;
            atomicAdd(&acc[bse + 0], vv);
            atomicAdd(&acc[bse + 1], vv + 1.0f);
            atomicAdd(&acc[bse + 2], vv + 2.0f);
            atomicAdd(&acc[bse + 3], vv + 3.0f);
        }
    }
    __syncthreads();
    if (n_raw == 0x7FFFFFFF) {
        #pragma unroll
        for (int j = 0; j < 4; ++j) sink[t + j * 256] = acc[(t + j * 256) % (TSPAT * LSTRIDE)];
    }
}

// PROBE 3: x loads only (identical addresses), folded to registers, no LDS atomics
__global__ __launch_bounds__(256, 8) void lss_probe_load(
    const unsigned* __restrict__ plist, const int* __restrict__ cnt,
    const float* __restrict__ x, float* __restrict__ sink)
{
    __shared__ unsigned ent[CAP];
    int tile = blockIdx.x;
    int t = threadIdx.x;
    int n_raw = cnt[tile * CNT_PAD];
    int n = n_raw > CAP ? CAP : n_raw;
    const unsigned* pl = plist + (size_t)tile * CAP;
    if (t < n) ent[t] = pl[t];
    __syncthreads();
    v4f sum = (v4f)(0.0f);
    if (n > 0) {
        int lane = t & 63, w = t >> 6, pg = lane >> 4, cg = lane & 15;
        int p0 = w * 4 + pg, coff = cg * 4;
        for (int p = p0; p < n; p += 16) {
            unsigned e = ent[p];
            v4f v = *(const v4f*)(x + ((size_t)(e >> 6)) * CDIM + coff);
            sum += v;                              // keep loads alive
        }
    }
    if (n_raw == 0x7FFFFFFF) {
        sink[t] = sum.x + sum.y + sum.z + sum.w;
    }
}

// Fallback (r5): direct atomics into out(b,c,s) if ws too small
__global__ __launch_bounds__(256) void lss_scatter_direct(
    const float* __restrict__ points, const float* __restrict__ x,
    float* __restrict__ out, int npoints, int per_batch)
{
    long long gid = (long long)blockIdx.x * blockDim.x + threadIdx.x;
    int wave = (int)(gid >> 6);
    int lane = (int)(gid & 63);
    if (wave >= npoints) return;
    float fx = points[(size_t)wave * 3 + 0];
    float fy = points[(size_t)wave * 3 + 1];
    float fz = points[(size_t)wave * 3 + 2];
    int px, py;
    if (!voxel_of(fx, fy, fz, px, py)) return;
    int b = (wave >= per_batch) ? 1 : 0;
    float v = x[(size_t)wave * CDIM + lane];
    size_t oidx = (((size_t)(b * CDIM + lane)) << 18) + ((size_t)px << 9) + (size_t)py;
    atomicAdd(out + oidx, v);
}

extern "C" void kernel_launch(void* const* d_in, const int* in_sizes, int n_in,
                              void* d_out, int out_size, void* d_ws, size_t ws_size,
                              hipStream_t stream) {
    const float* points = (const float*)d_in[0];
    const float* x      = (const float*)d_in[1];
    float* out = (float*)d_out;

    int npoints   = in_sizes[0] / 3;   // 826560
    int per_batch = npoints / 2;       // B = 2

    const size_t WS_CORE = (size_t)NTILE * CNT_PAD * 4 + (size_t)NTILE * CAP * 4;
    const size_t WS_PROBE = WS_CORE + 4096 * sizeof(float);

    if (ws_size >= WS_CORE) {
        int*      cnt   = (int*)d_ws;
        unsigned* plist = (unsigned*)(cnt + NTILE * CNT_PAD);
        float*    sink  = (float*)((char*)d_ws + WS_CORE);

        (void)hipMemsetAsync(cnt, 0, (size_t)NTILE * CNT_PAD * sizeof(int), stream);
        int pblocks = (npoints + 255) / 256;
        lss_bin  <<<pblocks, 256, 0, stream>>>(points, plist, cnt, npoints, per_batch);
        lss_accum<<<NTILE, 256, 0, stream>>>(plist, cnt, x, out);
        if (ws_size >= WS_PROBE) {
            lss_probe_empty<<<NTILE, 256, 0, stream>>>(cnt, sink);
            lss_probe_lds  <<<NTILE, 256, 0, stream>>>(plist, cnt, sink);
            lss_probe_load <<<NTILE, 256, 0, stream>>>(plist, cnt, x, sink);
        }
    } else {
        (void)hipMemsetAsync(d_out, 0, (size_t)out_size * sizeof(float), stream);
        long long total_threads = (long long)npoints * 64;
        int blocks = (int)((total_threads + 255) / 256);
        lss_scatter_direct<<<blocks, 256, 0, stream>>>(points, x, out, npoints, per_batch);
    }
}

// Round 17
// 90.253 us; speedup vs baseline: 4.8620x; 4.8620x over previous
//
#include <hip/hip_runtime.h>

// LiftSplatShot voxel pooling: segment-sum of per-point features into a
// (B=2, C=64, 512, 512) fp32 grid.
//
// NUMERICS (FROZEN — r5): jitted-XLA semantics
//   q = RN32( RN32(f + 51.2f) * 5.0f ) (x/y; recip(0.2f) folds to exactly 5.0f)
//   qz = RN32( RN32(f + 5.0f) * 0.125f ); trunc; kept: px,py in [0,512), pz==0.
//
// PERF r16 post-mortem: the cross-round invariant is an ATOMIC-OP RATE wall:
//   r5 scattered global atomics: 21 G lane-ops/s (1643us)
//   r6 line-grouped global atomics: 181 G/s (192us)
//   r8-r16 LDS ds_add_f32: 35.4M lane-ops / ~200us = 177 G/s (~0.7/cy/CU)
// LDS atomics serialize per-lane; plain LDS ops are 32-wide. r17: REMOVE ALL
// ATOMICS from accum via ownership: chunk of 16 points staged to LDS by all
// 4 waves, then wave w exclusively owns voxels s in [16w,16w+16) and does
// non-atomic acc[s][c] += stage[j][c]. Next chunk's global loads are issued
// before the own-phase (T14 issue-early) to hide latency.

#define NX0 512
#define NX1 512
#define CDIM 64
#define TSPAT 64             // 1(px) x 64(py) voxels per tile
#define NTILE 8192           // 2 * 512 * 8
#define CAP 256
#define LSTRIDE 65           // acc[s*65+c]: banks 2-way over 64 lanes
#define SSTRIDE 68           // stage row stride: 272B = 16B-aligned rows
#define CHUNK 16
#define CNT_PAD 16

typedef float v4f __attribute__((ext_vector_type(4)));

__device__ __forceinline__ bool voxel_of(float fx, float fy, float fz,
                                         int& px, int& py) {
    float qx = (fx + 51.2f) * 5.0f;
    float qy = (fy + 51.2f) * 5.0f;
    float qz = (fz + 5.0f) * 0.125f;
    px = (int)qx; py = (int)qy;
    int pz = (int)qz;
    return (px >= 0 && px < NX0 && py >= 0 && py < NX1 && pz == 0);
}

// A: bin points into fixed-capacity per-tile lists (unchanged, ~13us)
__global__ __launch_bounds__(256) void lss_bin(
    const float* __restrict__ points, unsigned* __restrict__ plist,
    int* __restrict__ cnt, int npoints, int per_batch)
{
    int i = blockIdx.x * 256 + threadIdx.x;
    if (i >= npoints) return;
    float fx = points[(size_t)i * 3 + 0];
    float fy = points[(size_t)i * 3 + 1];
    float fz = points[(size_t)i * 3 + 2];
    int px, py;
    if (!voxel_of(fx, fy, fz, px, py)) return;
    int b = (i >= per_batch) ? 1 : 0;
    unsigned tid = ((unsigned)b << 12) | ((unsigned)px << 3) | ((unsigned)py >> 6);
    unsigned s = (unsigned)(py & 63);
    int slot = atomicAdd(&cnt[tid * CNT_PAD], 1);
    if (slot < CAP) plist[(size_t)tid * CAP + slot] = ((unsigned)i << 6) | s;
}

// D: atomic-free accumulate via voxel-ownership partitioning
__global__ __launch_bounds__(256, 7) void lss_accum(
    const unsigned* __restrict__ plist, const int* __restrict__ cnt,
    const float* __restrict__ x, float* __restrict__ out)
{
    __shared__ float acc[TSPAT * LSTRIDE];      // 16.6 KB
    __shared__ float stage[CHUNK * SSTRIDE];    // 4.35 KB
    __shared__ int   schunk[CHUNK];
    __shared__ unsigned ent[CAP];               // 1 KB
    int tile = blockIdx.x;
    int t = threadIdx.x;

    int n = cnt[tile * CNT_PAD];
    if (n > CAP) n = CAP;

    {   // zero acc: 4160 floats = 1040 v4f
        v4f z = (v4f)(0.0f);
        v4f* a4 = (v4f*)acc;
        #pragma unroll
        for (int j = 0; j < 5; ++j) { int i = t + j * 256; if (i < 1040) a4[i] = z; }
    }
    const unsigned* pl = plist + (size_t)tile * CAP;
    if (t < n) ent[t] = pl[t];
    __syncthreads();

    int lane = t & 63, w = t >> 6;
    int pg = lane >> 4, cg = lane & 15;
    int slot = w * 4 + pg;          // this 16-lane group's stage slot (0..15)
    int coff = cg * 4;

    // prologue: load chunk 0 into regs
    v4f rv = (v4f)(0.0f); int rs = 0; bool ra = false;
    {
        int p = slot;
        ra = p < n;
        if (ra) {
            unsigned e = ent[p];
            rs = (int)(e & 63u);
            rv = *(const v4f*)(x + ((size_t)(e >> 6)) * CDIM + coff);
        }
    }

    for (int base = 0; base < n; base += CHUNK) {
        int m = n - base; if (m > CHUNK) m = CHUNK;

        // write current chunk regs -> stage
        if (ra) {
            *(v4f*)(stage + slot * SSTRIDE + coff) = rv;
            if (cg == 0) schunk[slot] = rs;
        }
        __syncthreads();

        // issue NEXT chunk's loads now (in flight during OWN phase)
        v4f rv2 = (v4f)(0.0f); int rs2 = 0; bool ra2 = false;
        {
            int p = base + CHUNK + slot;
            ra2 = p < n;
            if (ra2) {
                unsigned e = ent[p];
                rs2 = (int)(e & 63u);
                rv2 = *(const v4f*)(x + ((size_t)(e >> 6)) * CDIM + coff);
            }
        }

        // OWN: wave w exclusively owns voxels s in [16w, 16w+16) — no atomics
        for (int j = 0; j < m; ++j) {
            int s = schunk[j];                   // broadcast LDS read
            if ((s >> 4) == w) {                 // wave-uniform branch
                acc[s * LSTRIDE + lane] += stage[j * SSTRIDE + lane];
            }
        }
        __syncthreads();

        rv = rv2; rs = rs2; ra = ra2;
    }

    // epilogue (r14 winner): channel row = 256B contiguous per 16-lane group
    int b   = tile >> 12;
    int px  = (tile >> 3) & 511;
    int py0 = (tile & 7) << 6;
    int l16 = lane & 15, grp = lane >> 4;
    #pragma unroll
    for (int j = 0; j < 4; ++j) {
        int cc = j * 16 + w * 4 + grp;
        int sb = l16 * 4;
        v4f o;
        o.x = acc[(sb + 0) * LSTRIDE + cc];
        o.y = acc[(sb + 1) * LSTRIDE + cc];
        o.z = acc[(sb + 2) * LSTRIDE + cc];
        o.w = acc[(sb + 3) * LSTRIDE + cc];
        size_t oidx = (((size_t)(b * CDIM + cc)) << 18)
                    + ((size_t)px << 9) + (size_t)(py0 + sb);
        *(v4f*)(out + oidx) = o;
    }
}

// Fallback (r5): direct atomics into out(b,c,s) if ws too small
__global__ __launch_bounds__(256) void lss_scatter_direct(
    const float* __restrict__ points, const float* __restrict__ x,
    float* __restrict__ out, int npoints, int per_batch)
{
    long long gid = (long long)blockIdx.x * blockDim.x + threadIdx.x;
    int wave = (int)(gid >> 6);
    int lane = (int)(gid & 63);
    if (wave >= npoints) return;
    float fx = points[(size_t)wave * 3 + 0];
    float fy = points[(size_t)wave * 3 + 1];
    float fz = points[(size_t)wave * 3 + 2];
    int px, py;
    if (!voxel_of(fx, fy, fz, px, py)) return;
    int b = (wave >= per_batch) ? 1 : 0;
    float v = x[(size_t)wave * CDIM + lane];
    size_t oidx = (((size_t)(b * CDIM + lane)) << 18) + ((size_t)px << 9) + (size_t)py;
    atomicAdd(out + oidx, v);
}

extern "C" void kernel_launch(void* const* d_in, const int* in_sizes, int n_in,
                              void* d_out, int out_size, void* d_ws, size_t ws_size,
                              hipStream_t stream) {
    const float* points = (const float*)d_in[0];
    const float* x      = (const float*)d_in[1];
    float* out = (float*)d_out;

    int npoints   = in_sizes[0] / 3;   // 826560
    int per_batch = npoints / 2;       // B = 2

    const size_t WS_NEED = (size_t)NTILE * CNT_PAD * 4 + (size_t)NTILE * CAP * 4;

    if (ws_size >= WS_NEED) {
        int*      cnt   = (int*)d_ws;
        unsigned* plist = (unsigned*)(cnt + NTILE * CNT_PAD);

        (void)hipMemsetAsync(cnt, 0, (size_t)NTILE * CNT_PAD * sizeof(int), stream);
        int pblocks = (npoints + 255) / 256;
        lss_bin  <<<pblocks, 256, 0, stream>>>(points, plist, cnt, npoints, per_batch);
        lss_accum<<<NTILE, 256, 0, stream>>>(plist, cnt, x, out);
    } else {
        (void)hipMemsetAsync(d_out, 0, (size_t)out_size * sizeof(float), stream);
        long long total_threads = (long long)npoints * 64;
        int blocks = (int)((total_threads + 255) / 256);
        lss_scatter_direct<<<blocks, 256, 0, stream>>>(points, x, out, npoints, per_batch);
    }
}